// Round 1
// baseline (5709.191 us; speedup 1.0000x reference)
//
#include <hip/hip_runtime.h>
#include <math.h>

#define DIM 4096
#define RDIM 16
#define NPAIR 136
#define RIDGE 1e-5f

__device__ __forceinline__ int pidx(int r, int s) { // r <= s
    return r * (31 - r) / 2 + s;
}

// ---------------- transpose X -> Xt (Xt lives in d_out until final GEMM) ----
__global__ void __launch_bounds__(256) k_transpose(const float* __restrict__ X,
                                                   float* __restrict__ Xt) {
    __shared__ float tile[64][65];
    int bx = blockIdx.x, by = blockIdx.y;
    int lx = threadIdx.x & 63;
    int ly = threadIdx.x >> 6; // 0..3
#pragma unroll
    for (int i = 0; i < 16; ++i) {
        int r = ly + i * 4;
        tile[r][lx] = X[(size_t)(by * 64 + r) * DIM + bx * 64 + lx];
    }
    __syncthreads();
#pragma unroll
    for (int i = 0; i < 16; ++i) {
        int r = ly + i * 4;
        Xt[(size_t)(bx * 64 + r) * DIM + by * 64 + lx] = tile[lx][r];
    }
}

// ---------------- observed-count per column of Xp --------------------------
__global__ void __launch_bounds__(256) k_count(const float* __restrict__ Xp,
                                               float* __restrict__ cnt) {
    int c = blockIdx.x * 256 + threadIdx.x;
    int m0 = blockIdx.y * 256;
    float acc = 0.f;
    for (int m = 0; m < 256; ++m) {
        float x = Xp[(size_t)(m0 + m) * DIM + c];
        acc += (x != 0.f) ? 1.f : 0.f;
    }
    atomicAdd(&cnt[c], acc);
}

// ---------------- init copies ----------------------------------------------
__global__ void k_init_uc(const float* __restrict__ U, float* __restrict__ Uc) {
    int i = blockIdx.x * 256 + threadIdx.x;
    ((float4*)Uc)[i] = ((const float4*)U)[i];
}
__global__ void k_init_vt(const float* __restrict__ V, float* __restrict__ Vtb) {
    int n = blockIdx.x * 256 + threadIdx.x;
#pragma unroll
    for (int r = 0; r < RDIM; ++r) Vtb[(size_t)n * RDIM + r] = V[(size_t)r * DIM + n];
}

// ---------------- A[c] = sum_k w(k,c) * d_k d_k^T  (packed upper tri) ------
__global__ void __launch_bounds__(64) k_buildA(const float* __restrict__ Xp,
                                               const float* __restrict__ D,
                                               float* __restrict__ Apk) {
    __shared__ float ds[256 * RDIM];
    int c = blockIdx.x * 64 + threadIdx.x;
    int m0 = blockIdx.y * 256;
    // stage 256 design rows (4096 floats)
#pragma unroll
    for (int i = 0; i < 16; ++i)
        ((float4*)ds)[i * 64 + threadIdx.x] =
            ((const float4*)(D + (size_t)m0 * RDIM))[i * 64 + threadIdx.x];
    __syncthreads();

    float a[NPAIR];
#pragma unroll
    for (int i = 0; i < NPAIR; ++i) a[i] = 0.f;

    for (int m = 0; m < 256; ++m) {
        float x = Xp[(size_t)(m0 + m) * DIM + c];
        float u[RDIM];
#pragma unroll
        for (int q = 0; q < 4; ++q) {
            float4 t4 = ((const float4*)ds)[m * 4 + q];
            u[q * 4 + 0] = t4.x; u[q * 4 + 1] = t4.y;
            u[q * 4 + 2] = t4.z; u[q * 4 + 3] = t4.w;
        }
        bool w = (x != 0.f);
        float wu[RDIM];
#pragma unroll
        for (int r = 0; r < RDIM; ++r) wu[r] = w ? u[r] : 0.f;
#pragma unroll
        for (int r = 0; r < RDIM; ++r)
#pragma unroll
            for (int s = r; s < RDIM; ++s)
                a[pidx(r, s)] += wu[r] * u[s];
    }
#pragma unroll
    for (int i = 0; i < NPAIR; ++i)
        atomicAdd(&Apk[(size_t)c * NPAIR + i], a[i]);
}

// ---------------- invert 4096 16x16 SPD matrices; re-zero Apk; init sig ----
__global__ void __launch_bounds__(256) k_invert(float* __restrict__ Apk,
                                                float* __restrict__ Ainv,
                                                float* __restrict__ sig,
                                                const float* __restrict__ sigma) {
    int gt = blockIdx.x * 256 + threadIdx.x;
    int c = gt >> 4;
    int j = gt & 15;

    float a[RDIM], b[RDIM];
#pragma unroll
    for (int s = 0; s < RDIM; ++s) {
        int r0 = j < s ? j : s;
        int s0 = j < s ? s : j;
        a[s] = Apk[(size_t)c * NPAIR + pidx(r0, s0)];
        b[s] = 0.f;
    }
    a[j] += RIDGE;
    b[j] = 1.f;

#pragma unroll
    for (int k = 0; k < RDIM; ++k) {
        float pivA[RDIM], pivB[RDIM];
#pragma unroll
        for (int s = 0; s < RDIM; ++s) {
            pivA[s] = __shfl(a[s], k, 16);
            pivB[s] = __shfl(b[s], k, 16);
        }
        float pinv = 1.f / pivA[k];
        float f = a[k];
        if (j == k) {
#pragma unroll
            for (int s = 0; s < RDIM; ++s) { a[s] = pivA[s] * pinv; b[s] = pivB[s] * pinv; }
        } else {
#pragma unroll
            for (int s = 0; s < RDIM; ++s) {
                a[s] -= f * pinv * pivA[s];
                b[s] -= f * pinv * pivB[s];
            }
        }
    }
#pragma unroll
    for (int s = 0; s < RDIM; ++s) Ainv[(size_t)c * 256 + j * 16 + s] = b[s];
    // re-zero packed A for the next buildA
#pragma unroll
    for (int q = 0; q < 9; ++q) {
        int idx = j * 9 + q;
        if (idx < NPAIR) Apk[(size_t)c * NPAIR + idx] = 0.f;
    }
    if (j == 0) sig[c] = sigma[0];
}

// ---------------- pass 1: column sums of psi^2 -----------------------------
template <int ROWS>
__global__ void __launch_bounds__(256) k_it_a(const float* __restrict__ Xp,
                                              const float* __restrict__ D,
                                              const float* __restrict__ B,
                                              const float* __restrict__ sig,
                                              const float* __restrict__ cvec, int layer,
                                              float* __restrict__ spsi) {
    __shared__ float ds[ROWS * RDIM];
    int c = blockIdx.x * 256 + threadIdx.x;
    int m0 = blockIdx.y * ROWS;
#pragma unroll
    for (int i = 0; i < ROWS / 64; ++i)
        ((float4*)ds)[i * 256 + threadIdx.x] =
            ((const float4*)(D + (size_t)m0 * RDIM))[i * 256 + threadIdx.x];
    float beta[RDIM];
#pragma unroll
    for (int q = 0; q < 4; ++q) {
        float4 t4 = ((const float4*)(B + (size_t)c * RDIM))[q];
        beta[q * 4 + 0] = t4.x; beta[q * 4 + 1] = t4.y;
        beta[q * 4 + 2] = t4.z; beta[q * 4 + 3] = t4.w;
    }
    float sg = sig[c];
    float cl = cvec[layer];
    float inv_sg = 1.f / sg;
    __syncthreads();

    float acc = 0.f;
    for (int m = 0; m < ROWS; ++m) {
        float x = Xp[(size_t)(m0 + m) * DIM + c];
        float dot = 0.f;
#pragma unroll
        for (int q = 0; q < 4; ++q) {
            float4 u4 = ((const float4*)ds)[m * 4 + q];
            dot += u4.x * beta[q * 4 + 0] + u4.y * beta[q * 4 + 1] +
                   u4.z * beta[q * 4 + 2] + u4.w * beta[q * 4 + 3];
        }
        float res = (x != 0.f) ? (x - dot) : 0.f;
        float psi = fminf(fmaxf(res * inv_sg, -cl), cl);
        acc += psi * psi;
    }
    atomicAdd(&spsi[c], acc);
}

// ---------------- sigma update; zero spsi + t ------------------------------
__global__ void k_it_b(float* __restrict__ spsi, const float* __restrict__ cnt,
                       const float* __restrict__ cvec, const float* __restrict__ lvec,
                       int layer, float* __restrict__ sig, float* __restrict__ tbuf) {
    int c = blockIdx.x * 256 + threadIdx.x;
    float cl = cvec[layer], ll = lvec[layer];
    // alpha = c(1-erf(sqrt(c))) + 0.5(erf(c/sqrt2) - sqrt(2/pi) c e^{-c^2/2})
    float alpha = cl * (1.f - erff(sqrtf(cl))) +
                  0.5f * (erff(cl * 0.70710678118f) -
                          0.79788456080f * cl * expf(-0.5f * cl * cl));
    float tau = sqrtf(spsi[c]) / sqrtf(2.f * cnt[c] * alpha);
    sig[c] = tau * ll;
    spsi[c] = 0.f;
    float4 z = make_float4(0.f, 0.f, 0.f, 0.f);
#pragma unroll
    for (int q = 0; q < 4; ++q) ((float4*)(tbuf + (size_t)c * RDIM))[q] = z;
}

// ---------------- pass 2: t[c] = sum_k d_k * (w psi2 sig) ------------------
template <int ROWS>
__global__ void __launch_bounds__(256) k_it_c(const float* __restrict__ Xp,
                                              const float* __restrict__ D,
                                              const float* __restrict__ B,
                                              const float* __restrict__ sig,
                                              const float* __restrict__ cvec, int layer,
                                              float* __restrict__ tbuf) {
    __shared__ float ds[ROWS * RDIM];
    int c = blockIdx.x * 256 + threadIdx.x;
    int m0 = blockIdx.y * ROWS;
#pragma unroll
    for (int i = 0; i < ROWS / 64; ++i)
        ((float4*)ds)[i * 256 + threadIdx.x] =
            ((const float4*)(D + (size_t)m0 * RDIM))[i * 256 + threadIdx.x];
    float beta[RDIM];
#pragma unroll
    for (int q = 0; q < 4; ++q) {
        float4 t4 = ((const float4*)(B + (size_t)c * RDIM))[q];
        beta[q * 4 + 0] = t4.x; beta[q * 4 + 1] = t4.y;
        beta[q * 4 + 2] = t4.z; beta[q * 4 + 3] = t4.w;
    }
    float sg = sig[c];
    float cl = cvec[layer];
    float inv_sg = 1.f / sg;
    __syncthreads();

    float tac[RDIM];
#pragma unroll
    for (int r = 0; r < RDIM; ++r) tac[r] = 0.f;

    for (int m = 0; m < ROWS; ++m) {
        float x = Xp[(size_t)(m0 + m) * DIM + c];
        float u[RDIM];
#pragma unroll
        for (int q = 0; q < 4; ++q) {
            float4 u4 = ((const float4*)ds)[m * 4 + q];
            u[q * 4 + 0] = u4.x; u[q * 4 + 1] = u4.y;
            u[q * 4 + 2] = u4.z; u[q * 4 + 3] = u4.w;
        }
        float dot = 0.f;
#pragma unroll
        for (int r = 0; r < RDIM; ++r) dot += u[r] * beta[r];
        float res = (x != 0.f) ? (x - dot) : 0.f;
        float psi2 = fminf(fmaxf(res * inv_sg, -cl), cl);
        float coeff = psi2 * sg;
#pragma unroll
        for (int r = 0; r < RDIM; ++r) tac[r] += u[r] * coeff;
    }
#pragma unroll
    for (int r = 0; r < RDIM; ++r)
        atomicAdd(&tbuf[(size_t)c * RDIM + r], tac[r]);
}

// ---------------- beta update: B[c] += mu * Ainv[c] @ t[c] -----------------
__global__ void k_it_d(const float* __restrict__ Ainv, const float* __restrict__ tbuf,
                       const float* __restrict__ mvec, int layer, float* __restrict__ B) {
    int c = blockIdx.x * 256 + threadIdx.x;
    float ml = mvec[layer];
    float t[RDIM];
#pragma unroll
    for (int q = 0; q < 4; ++q) {
        float4 t4 = ((const float4*)(tbuf + (size_t)c * RDIM))[q];
        t[q * 4 + 0] = t4.x; t[q * 4 + 1] = t4.y;
        t[q * 4 + 2] = t4.z; t[q * 4 + 3] = t4.w;
    }
#pragma unroll
    for (int r = 0; r < RDIM; ++r) {
        float d = 0.f;
#pragma unroll
        for (int s = 0; s < RDIM; ++s)
            d += Ainv[(size_t)c * 256 + r * 16 + s] * t[s];
        B[(size_t)c * RDIM + r] += ml * d;
    }
}

// ---------------- final out = Uc @ Vtb^T -----------------------------------
__global__ void __launch_bounds__(256) k_out(const float* __restrict__ Uc,
                                             const float* __restrict__ Vtb,
                                             float* __restrict__ out) {
    __shared__ float us[64 * RDIM];
    int j = blockIdx.x * 256 + threadIdx.x;
    int i0 = blockIdx.y * 64;
    ((float4*)us)[threadIdx.x] = ((const float4*)(Uc + (size_t)i0 * RDIM))[threadIdx.x];
    float beta[RDIM];
#pragma unroll
    for (int q = 0; q < 4; ++q) {
        float4 t4 = ((const float4*)(Vtb + (size_t)j * RDIM))[q];
        beta[q * 4 + 0] = t4.x; beta[q * 4 + 1] = t4.y;
        beta[q * 4 + 2] = t4.z; beta[q * 4 + 3] = t4.w;
    }
    __syncthreads();
#pragma unroll 4
    for (int r = 0; r < 64; ++r) {
        float dot = 0.f;
#pragma unroll
        for (int q = 0; q < 4; ++q) {
            float4 u4 = ((const float4*)us)[r * 4 + q];
            dot += u4.x * beta[q * 4 + 0] + u4.y * beta[q * 4 + 1] +
                   u4.z * beta[q * 4 + 2] + u4.w * beta[q * 4 + 3];
        }
        out[(size_t)(i0 + r) * DIM + j] = dot;
    }
}

extern "C" void kernel_launch(void* const* d_in, const int* in_sizes, int n_in,
                              void* d_out, int out_size, void* d_ws, size_t ws_size,
                              hipStream_t stream) {
    const float* U = (const float*)d_in[0];
    const float* V = (const float*)d_in[1];
    const float* X = (const float*)d_in[2];
    const float* cvec = (const float*)d_in[3];
    const float* lvec = (const float*)d_in[4];
    const float* mvec = (const float*)d_in[5];
    const float* sigma = (const float*)d_in[6];
    float* out = (float*)d_out;

    float* ws = (float*)d_ws;
    float* Apk  = ws;                               // 4096*136
    float* spsi = Apk + (size_t)DIM * NPAIR;        // 4096
    float* cntc = spsi + DIM;                       // 4096
    float* cntr = cntc + DIM;                       // 4096
    float* Uc   = cntr + DIM;                       // 4096*16
    float* Vtb  = Uc + (size_t)DIM * RDIM;          // 4096*16
    float* Ainv = Vtb + (size_t)DIM * RDIM;         // 4096*256
    float* tbuf = Ainv + (size_t)DIM * 256;         // 4096*16
    float* sig  = tbuf + (size_t)DIM * RDIM;        // 4096
    float* Xt   = out;  // reuse d_out as transpose scratch until k_out

    // zero atomically-accumulated regions (Apk, spsi, cntc, cntr) — contiguous
    hipMemsetAsync(d_ws, 0, (size_t)(DIM * NPAIR + 3 * DIM) * sizeof(float), stream);

    k_transpose<<<dim3(64, 64), 256, 0, stream>>>(X, Xt);
    k_init_uc<<<64, 256, 0, stream>>>(U, Uc);
    k_init_vt<<<16, 256, 0, stream>>>(V, Vtb);
    k_count<<<dim3(16, 16), 256, 0, stream>>>(X, cntc);
    k_count<<<dim3(16, 16), 256, 0, stream>>>(Xt, cntr);

    for (int layer = 0; layer < 3; ++layer) {
        // ---- V step: columns of X, design rows = Uc ----
        k_buildA<<<dim3(64, 16), 64, 0, stream>>>(X, Uc, Apk);
        k_invert<<<256, 256, 0, stream>>>(Apk, Ainv, sig, sigma);
        for (int it = 0; it < 2; ++it) {
            k_it_a<128><<<dim3(16, 32), 256, 0, stream>>>(X, Uc, Vtb, sig, cvec, layer, spsi);
            k_it_b<<<16, 256, 0, stream>>>(spsi, cntc, cvec, lvec, layer, sig, tbuf);
            k_it_c<128><<<dim3(16, 32), 256, 0, stream>>>(X, Uc, Vtb, sig, cvec, layer, tbuf);
            k_it_d<<<16, 256, 0, stream>>>(Ainv, tbuf, mvec, layer, Vtb);
        }
        // ---- U step: columns of Xt (= rows of X), design rows = Vtb ----
        k_buildA<<<dim3(64, 16), 64, 0, stream>>>(Xt, Vtb, Apk);
        k_invert<<<256, 256, 0, stream>>>(Apk, Ainv, sig, sigma);
        for (int it = 0; it < 2; ++it) {
            k_it_a<128><<<dim3(16, 32), 256, 0, stream>>>(Xt, Vtb, Uc, sig, cvec, layer, spsi);
            k_it_b<<<16, 256, 0, stream>>>(spsi, cntr, cvec, lvec, layer, sig, tbuf);
            k_it_c<128><<<dim3(16, 32), 256, 0, stream>>>(Xt, Vtb, Uc, sig, cvec, layer, tbuf);
            k_it_d<<<16, 256, 0, stream>>>(Ainv, tbuf, mvec, layer, Uc);
        }
    }
    k_out<<<dim3(16, 64), 256, 0, stream>>>(Uc, Vtb, out);
}

// Round 2
// 4978.654 us; speedup vs baseline: 1.1467x; 1.1467x over previous
//
#include <hip/hip_runtime.h>
#include <math.h>

#define DIM 4096
#define RDIM 16
#define RIDGE 1e-5f
#define NCHUNK 4   // buildA m-chunks (1024 rows each)

// ---------------- transpose X -> Xt (Xt lives in d_out until final GEMM) ----
__global__ void __launch_bounds__(256) k_transpose(const float* __restrict__ X,
                                                   float* __restrict__ Xt) {
    __shared__ float tile[64][65];
    int bx = blockIdx.x, by = blockIdx.y;
    int lx = threadIdx.x & 63;
    int ly = threadIdx.x >> 6; // 0..3
#pragma unroll
    for (int i = 0; i < 16; ++i) {
        int r = ly + i * 4;
        tile[r][lx] = X[(size_t)(by * 64 + r) * DIM + bx * 64 + lx];
    }
    __syncthreads();
#pragma unroll
    for (int i = 0; i < 16; ++i) {
        int r = ly + i * 4;
        Xt[(size_t)(bx * 64 + r) * DIM + by * 64 + lx] = tile[lx][r];
    }
}

// ---------------- observed-count per column of Xp --------------------------
__global__ void __launch_bounds__(256) k_count(const float* __restrict__ Xp,
                                               float* __restrict__ cnt) {
    int c = blockIdx.x * 256 + threadIdx.x;
    int m0 = blockIdx.y * 256;
    float acc = 0.f;
    for (int m = 0; m < 256; ++m) {
        float x = Xp[(size_t)(m0 + m) * DIM + c];
        acc += (x != 0.f) ? 1.f : 0.f;
    }
    atomicAdd(&cnt[c], acc);
}

// ---------------- init copies ----------------------------------------------
__global__ void k_init_uc(const float* __restrict__ U, float* __restrict__ Uc) {
    int i = blockIdx.x * 256 + threadIdx.x;
    ((float4*)Uc)[i] = ((const float4*)U)[i];
}
__global__ void k_init_vt(const float* __restrict__ V, float* __restrict__ Vtb) {
    int n = blockIdx.x * 256 + threadIdx.x;
#pragma unroll
    for (int r = 0; r < RDIM; ++r) Vtb[(size_t)n * RDIM + r] = V[(size_t)r * DIM + n];
}

// ---------------- A partials: Apart[ch][c][j][s] = sum_m w*u_j*u_s ---------
// block = 256 threads: g = tid&15 (column group of 4), j = tid>>4 (A row).
// grid = (64 col-blocks of 64 cols, NCHUNK m-chunks of 1024 rows).
__global__ void __launch_bounds__(256) k_buildA(const float* __restrict__ Xp,
                                                const float* __restrict__ D,
                                                float* __restrict__ Apart) {
    __shared__ float ds[128 * RDIM]; // 8 KB: 128 design rows
    const int g = threadIdx.x & 15;
    const int j = threadIdx.x >> 4;
    const int cbase = blockIdx.x * 64 + g * 4;
    const int m0 = blockIdx.y * 1024;

    float a[4][16];
#pragma unroll
    for (int i = 0; i < 4; ++i)
#pragma unroll
        for (int s = 0; s < 16; ++s) a[i][s] = 0.f;

    for (int sub = 0; sub < 8; ++sub) {
        const float* Dsub = D + (size_t)(m0 + sub * 128) * RDIM;
        ((float4*)ds)[threadIdx.x]       = ((const float4*)Dsub)[threadIdx.x];
        ((float4*)ds)[256 + threadIdx.x] = ((const float4*)Dsub)[256 + threadIdx.x];
        __syncthreads();

        for (int m = 0; m < 128; ++m) {
            float4 x4 = *(const float4*)(Xp + (size_t)(m0 + sub * 128 + m) * DIM + cbase);
            float u[16];
#pragma unroll
            for (int q = 0; q < 4; ++q) {
                float4 u4 = ((const float4*)(ds + m * RDIM))[q];
                u[q * 4 + 0] = u4.x; u[q * 4 + 1] = u4.y;
                u[q * 4 + 2] = u4.z; u[q * 4 + 3] = u4.w;
            }
            float uj = ds[m * RDIM + j];
            float p0 = (x4.x != 0.f) ? uj : 0.f;
            float p1 = (x4.y != 0.f) ? uj : 0.f;
            float p2 = (x4.z != 0.f) ? uj : 0.f;
            float p3 = (x4.w != 0.f) ? uj : 0.f;
#pragma unroll
            for (int s = 0; s < 16; ++s) {
                a[0][s] += p0 * u[s];
                a[1][s] += p1 * u[s];
                a[2][s] += p2 * u[s];
                a[3][s] += p3 * u[s];
            }
        }
        __syncthreads();
    }
#pragma unroll
    for (int i = 0; i < 4; ++i) {
        size_t base = (((size_t)blockIdx.y * DIM + (cbase + i)) * RDIM + j) * RDIM;
#pragma unroll
        for (int q = 0; q < 4; ++q)
            *(float4*)(Apart + base + q * 4) =
                make_float4(a[i][q * 4 + 0], a[i][q * 4 + 1], a[i][q * 4 + 2], a[i][q * 4 + 3]);
    }
}

// ------- reduce Apart chunks, invert 4096 16x16 SPD matrices, init sig -----
__global__ void __launch_bounds__(256) k_invert(const float* __restrict__ Apart,
                                                float* __restrict__ Ainv,
                                                float* __restrict__ sig,
                                                const float* __restrict__ sigma) {
    int gt = blockIdx.x * 256 + threadIdx.x;
    int c = gt >> 4;
    int j = gt & 15;

    float a[16], b[16];
#pragma unroll
    for (int s = 0; s < 16; ++s) { a[s] = 0.f; b[s] = 0.f; }
#pragma unroll
    for (int ch = 0; ch < NCHUNK; ++ch) {
        size_t base = (((size_t)ch * DIM + c) * RDIM + j) * RDIM;
#pragma unroll
        for (int q = 0; q < 4; ++q) {
            float4 t = *(const float4*)(Apart + base + q * 4);
            a[q * 4 + 0] += t.x; a[q * 4 + 1] += t.y;
            a[q * 4 + 2] += t.z; a[q * 4 + 3] += t.w;
        }
    }
    a[j] += RIDGE;
    b[j] = 1.f;

#pragma unroll
    for (int k = 0; k < RDIM; ++k) {
        float pivA[16], pivB[16];
#pragma unroll
        for (int s = 0; s < 16; ++s) {
            pivA[s] = __shfl(a[s], k, 16);
            pivB[s] = __shfl(b[s], k, 16);
        }
        float pinv = 1.f / pivA[k];
        float f = a[k];
        if (j == k) {
#pragma unroll
            for (int s = 0; s < 16; ++s) { a[s] = pivA[s] * pinv; b[s] = pivB[s] * pinv; }
        } else {
#pragma unroll
            for (int s = 0; s < 16; ++s) {
                a[s] -= f * pinv * pivA[s];
                b[s] -= f * pinv * pivB[s];
            }
        }
    }
#pragma unroll
    for (int s = 0; s < 16; ++s) Ainv[(size_t)c * 256 + j * 16 + s] = b[s];
    if (j == 0) sig[c] = sigma[0];
}

// ---------------- pass 1: column sums of psi^2 (T=4 cols/thread) -----------
template <int ROWS>
__global__ void __launch_bounds__(256) k_it_a(const float* __restrict__ Xp,
                                              const float* __restrict__ D,
                                              const float* __restrict__ B,
                                              const float* __restrict__ sig,
                                              const float* __restrict__ cvec, int layer,
                                              float* __restrict__ spsi) {
    __shared__ float ds[ROWS * RDIM];
    const int c = blockIdx.x * 1024 + threadIdx.x * 4;
    const int m0 = blockIdx.y * ROWS;
    constexpr int NV = ROWS * RDIM / 4;
    for (int i = threadIdx.x; i < NV; i += 256)
        ((float4*)ds)[i] = ((const float4*)(D + (size_t)m0 * RDIM))[i];

    float beta[4][16], invsg[4];
#pragma unroll
    for (int i = 0; i < 4; ++i) {
#pragma unroll
        for (int q = 0; q < 4; ++q) {
            float4 t4 = ((const float4*)(B + (size_t)(c + i) * RDIM))[q];
            beta[i][q * 4 + 0] = t4.x; beta[i][q * 4 + 1] = t4.y;
            beta[i][q * 4 + 2] = t4.z; beta[i][q * 4 + 3] = t4.w;
        }
        invsg[i] = 1.f / sig[c + i];
    }
    float cl = cvec[layer];
    __syncthreads();

    float acc[4] = {0.f, 0.f, 0.f, 0.f};
    for (int m = 0; m < ROWS; ++m) {
        float u[16];
#pragma unroll
        for (int q = 0; q < 4; ++q) {
            float4 u4 = ((const float4*)(ds + m * RDIM))[q];
            u[q * 4 + 0] = u4.x; u[q * 4 + 1] = u4.y;
            u[q * 4 + 2] = u4.z; u[q * 4 + 3] = u4.w;
        }
        float4 x4 = *(const float4*)(Xp + (size_t)(m0 + m) * DIM + c);
        float xv[4] = {x4.x, x4.y, x4.z, x4.w};
#pragma unroll
        for (int i = 0; i < 4; ++i) {
            float dot = 0.f;
#pragma unroll
            for (int s = 0; s < 16; ++s) dot += u[s] * beta[i][s];
            float res = (xv[i] != 0.f) ? (xv[i] - dot) : 0.f;
            float psi = fminf(fmaxf(res * invsg[i], -cl), cl);
            acc[i] += psi * psi;
        }
    }
#pragma unroll
    for (int i = 0; i < 4; ++i) atomicAdd(&spsi[c + i], acc[i]);
}

// ---------------- sigma update; zero spsi + t ------------------------------
__global__ void k_it_b(float* __restrict__ spsi, const float* __restrict__ cnt,
                       const float* __restrict__ cvec, const float* __restrict__ lvec,
                       int layer, float* __restrict__ sig, float* __restrict__ tbuf) {
    int c = blockIdx.x * 256 + threadIdx.x;
    float cl = cvec[layer], ll = lvec[layer];
    float alpha = cl * (1.f - erff(sqrtf(cl))) +
                  0.5f * (erff(cl * 0.70710678118f) -
                          0.79788456080f * cl * expf(-0.5f * cl * cl));
    float tau = sqrtf(spsi[c]) / sqrtf(2.f * cnt[c] * alpha);
    sig[c] = tau * ll;
    spsi[c] = 0.f;
    float4 z = make_float4(0.f, 0.f, 0.f, 0.f);
#pragma unroll
    for (int q = 0; q < 4; ++q) ((float4*)(tbuf + (size_t)c * RDIM))[q] = z;
}

// ---------------- pass 2: t[c] += sum_m u_m * (w psi2 sig), T=4 ------------
template <int ROWS>
__global__ void __launch_bounds__(256) k_it_c(const float* __restrict__ Xp,
                                              const float* __restrict__ D,
                                              const float* __restrict__ B,
                                              const float* __restrict__ sig,
                                              const float* __restrict__ cvec, int layer,
                                              float* __restrict__ tbuf) {
    __shared__ float ds[ROWS * RDIM];
    const int c = blockIdx.x * 1024 + threadIdx.x * 4;
    const int m0 = blockIdx.y * ROWS;
    constexpr int NV = ROWS * RDIM / 4;
    for (int i = threadIdx.x; i < NV; i += 256)
        ((float4*)ds)[i] = ((const float4*)(D + (size_t)m0 * RDIM))[i];

    float beta[4][16], sg[4], invsg[4];
#pragma unroll
    for (int i = 0; i < 4; ++i) {
#pragma unroll
        for (int q = 0; q < 4; ++q) {
            float4 t4 = ((const float4*)(B + (size_t)(c + i) * RDIM))[q];
            beta[i][q * 4 + 0] = t4.x; beta[i][q * 4 + 1] = t4.y;
            beta[i][q * 4 + 2] = t4.z; beta[i][q * 4 + 3] = t4.w;
        }
        sg[i] = sig[c + i];
        invsg[i] = 1.f / sg[i];
    }
    float cl = cvec[layer];
    __syncthreads();

    float tac[4][16];
#pragma unroll
    for (int i = 0; i < 4; ++i)
#pragma unroll
        for (int s = 0; s < 16; ++s) tac[i][s] = 0.f;

    for (int m = 0; m < ROWS; ++m) {
        float u[16];
#pragma unroll
        for (int q = 0; q < 4; ++q) {
            float4 u4 = ((const float4*)(ds + m * RDIM))[q];
            u[q * 4 + 0] = u4.x; u[q * 4 + 1] = u4.y;
            u[q * 4 + 2] = u4.z; u[q * 4 + 3] = u4.w;
        }
        float4 x4 = *(const float4*)(Xp + (size_t)(m0 + m) * DIM + c);
        float xv[4] = {x4.x, x4.y, x4.z, x4.w};
#pragma unroll
        for (int i = 0; i < 4; ++i) {
            float dot = 0.f;
#pragma unroll
            for (int s = 0; s < 16; ++s) dot += u[s] * beta[i][s];
            float res = (xv[i] != 0.f) ? (xv[i] - dot) : 0.f;
            float psi2 = fminf(fmaxf(res * invsg[i], -cl), cl);
            float coeff = psi2 * sg[i];
#pragma unroll
            for (int s = 0; s < 16; ++s) tac[i][s] += u[s] * coeff;
        }
    }
#pragma unroll
    for (int i = 0; i < 4; ++i)
#pragma unroll
        for (int s = 0; s < 16; ++s)
            atomicAdd(&tbuf[(size_t)(c + i) * RDIM + s], tac[i][s]);
}

// ---------------- beta update: B[c] += mu * Ainv[c] @ t[c] -----------------
__global__ void k_it_d(const float* __restrict__ Ainv, const float* __restrict__ tbuf,
                       const float* __restrict__ mvec, int layer, float* __restrict__ B) {
    int c = blockIdx.x * 256 + threadIdx.x;
    float ml = mvec[layer];
    float t[16];
#pragma unroll
    for (int q = 0; q < 4; ++q) {
        float4 t4 = ((const float4*)(tbuf + (size_t)c * RDIM))[q];
        t[q * 4 + 0] = t4.x; t[q * 4 + 1] = t4.y;
        t[q * 4 + 2] = t4.z; t[q * 4 + 3] = t4.w;
    }
#pragma unroll
    for (int r = 0; r < RDIM; ++r) {
        float d = 0.f;
#pragma unroll
        for (int s = 0; s < RDIM; ++s)
            d += Ainv[(size_t)c * 256 + r * 16 + s] * t[s];
        B[(size_t)c * RDIM + r] += ml * d;
    }
}

// ---------------- final out = Uc @ Vtb^T -----------------------------------
__global__ void __launch_bounds__(256) k_out(const float* __restrict__ Uc,
                                             const float* __restrict__ Vtb,
                                             float* __restrict__ out) {
    __shared__ float us[64 * RDIM];
    int j = blockIdx.x * 256 + threadIdx.x;
    int i0 = blockIdx.y * 64;
    ((float4*)us)[threadIdx.x] = ((const float4*)(Uc + (size_t)i0 * RDIM))[threadIdx.x];
    float beta[16];
#pragma unroll
    for (int q = 0; q < 4; ++q) {
        float4 t4 = ((const float4*)(Vtb + (size_t)j * RDIM))[q];
        beta[q * 4 + 0] = t4.x; beta[q * 4 + 1] = t4.y;
        beta[q * 4 + 2] = t4.z; beta[q * 4 + 3] = t4.w;
    }
    __syncthreads();
#pragma unroll 4
    for (int r = 0; r < 64; ++r) {
        float dot = 0.f;
#pragma unroll
        for (int q = 0; q < 4; ++q) {
            float4 u4 = ((const float4*)(us + r * RDIM))[q];
            dot += u4.x * beta[q * 4 + 0] + u4.y * beta[q * 4 + 1] +
                   u4.z * beta[q * 4 + 2] + u4.w * beta[q * 4 + 3];
        }
        out[(size_t)(i0 + r) * DIM + j] = dot;
    }
}

extern "C" void kernel_launch(void* const* d_in, const int* in_sizes, int n_in,
                              void* d_out, int out_size, void* d_ws, size_t ws_size,
                              hipStream_t stream) {
    const float* U = (const float*)d_in[0];
    const float* V = (const float*)d_in[1];
    const float* X = (const float*)d_in[2];
    const float* cvec = (const float*)d_in[3];
    const float* lvec = (const float*)d_in[4];
    const float* mvec = (const float*)d_in[5];
    const float* sigma = (const float*)d_in[6];
    float* out = (float*)d_out;

    float* ws = (float*)d_ws;
    float* Apart = ws;                                   // NCHUNK*4096*256
    float* spsi  = Apart + (size_t)NCHUNK * DIM * 256;   // 4096
    float* cntc  = spsi + DIM;                           // 4096
    float* cntr  = cntc + DIM;                           // 4096
    float* sig   = cntr + DIM;                           // 4096
    float* Uc    = sig + DIM;                            // 4096*16
    float* Vtb   = Uc + (size_t)DIM * RDIM;              // 4096*16
    float* tbuf  = Vtb + (size_t)DIM * RDIM;             // 4096*16
    float* Ainv  = tbuf + (size_t)DIM * RDIM;            // 4096*256
    float* Xt    = out;  // reuse d_out as transpose scratch until k_out

    // zero atomic targets: spsi, cntc, cntr (contiguous)
    hipMemsetAsync(spsi, 0, (size_t)3 * DIM * sizeof(float), stream);

    k_transpose<<<dim3(64, 64), 256, 0, stream>>>(X, Xt);
    k_init_uc<<<64, 256, 0, stream>>>(U, Uc);
    k_init_vt<<<16, 256, 0, stream>>>(V, Vtb);
    k_count<<<dim3(16, 16), 256, 0, stream>>>(X, cntc);
    k_count<<<dim3(16, 16), 256, 0, stream>>>(Xt, cntr);

    for (int layer = 0; layer < 3; ++layer) {
        // ---- V step: columns of X, design rows = Uc ----
        k_buildA<<<dim3(64, NCHUNK), 256, 0, stream>>>(X, Uc, Apart);
        k_invert<<<256, 256, 0, stream>>>(Apart, Ainv, sig, sigma);
        for (int it = 0; it < 2; ++it) {
            k_it_a<32><<<dim3(4, 128), 256, 0, stream>>>(X, Uc, Vtb, sig, cvec, layer, spsi);
            k_it_b<<<16, 256, 0, stream>>>(spsi, cntc, cvec, lvec, layer, sig, tbuf);
            k_it_c<64><<<dim3(4, 64), 256, 0, stream>>>(X, Uc, Vtb, sig, cvec, layer, tbuf);
            k_it_d<<<16, 256, 0, stream>>>(Ainv, tbuf, mvec, layer, Vtb);
        }
        // ---- U step: columns of Xt (= rows of X), design rows = Vtb ----
        k_buildA<<<dim3(64, NCHUNK), 256, 0, stream>>>(Xt, Vtb, Apart);
        k_invert<<<256, 256, 0, stream>>>(Apart, Ainv, sig, sigma);
        for (int it = 0; it < 2; ++it) {
            k_it_a<32><<<dim3(4, 128), 256, 0, stream>>>(Xt, Vtb, Uc, sig, cvec, layer, spsi);
            k_it_b<<<16, 256, 0, stream>>>(spsi, cntr, cvec, lvec, layer, sig, tbuf);
            k_it_c<64><<<dim3(4, 64), 256, 0, stream>>>(Xt, Vtb, Uc, sig, cvec, layer, tbuf);
            k_it_d<<<16, 256, 0, stream>>>(Ainv, tbuf, mvec, layer, Uc);
        }
    }
    k_out<<<dim3(16, 64), 256, 0, stream>>>(Uc, Vtb, out);
}